// Round 2
// baseline (462.084 us; speedup 1.0000x reference)
//
#include <hip/hip_runtime.h>

// LGCN_REL_EMB: relational graph conv with identity relation embeddings.
//   cnt[r*N+v]  = #{t : rel[t]==r, fr[t]==v}
//   inv         = 1/cnt (0 where cnt==0)
//   h[v,:]      = relu(bias1 + sum_t inv[rel,fr] * w1[rel, to, :])   for fr[t]==v
//   out[v,c]    = bias2[c] + sum_t inv[rel,fr] * dot(h[to,:], w2[rel,:,c])  for fr[t]==v
//
// Fixed problem constants (from reference): R=16, E=32, C=50.

#define RP 16
#define EDIM 32
#define CDIM 50
#define LDSPAD 52   // row pad to 52 floats -> 208B rows, keeps float4 16B-aligned

__global__ void k_count(const int* __restrict__ fr, const int* __restrict__ rel,
                        int* __restrict__ cnt, int T, int N) {
    int t = blockIdx.x * blockDim.x + threadIdx.x;
    if (t < T) atomicAdd(&cnt[rel[t] * N + fr[t]], 1);
}

__global__ void k_inv(const int* __restrict__ cnt, float* __restrict__ inv, int n) {
    int i = blockIdx.x * blockDim.x + threadIdx.x;
    if (i < n) {
        int c = cnt[i];
        inv[i] = (c > 0) ? 1.0f / (float)c : 0.0f;
    }
}

// one thread per (triple, e-quad): h[fr*32 + q*4 .. +3] += inv * w1[(rel*N+to)*32 + q*4 ..]
__global__ void k_spmm1(const int* __restrict__ fr, const int* __restrict__ to,
                        const int* __restrict__ rel, const float* __restrict__ w1,
                        const float* __restrict__ inv, float* __restrict__ h,
                        int T, int N) {
    int idx = blockIdx.x * blockDim.x + threadIdx.x;
    int t = idx >> 3;     // E/4 = 8 quads per triple
    int q = idx & 7;
    if (t < T) {
        int r = rel[t], f = fr[t], o = to[t];
        float w = inv[r * N + f];   // always > 0 for a live triple
        const float4 v = *reinterpret_cast<const float4*>(
            w1 + ((size_t)r * N + o) * EDIM + q * 4);
        float* hp = h + (size_t)f * EDIM + q * 4;
        atomicAdd(hp + 0, w * v.x);
        atomicAdd(hp + 1, w * v.y);
        atomicAdd(hp + 2, w * v.z);
        atomicAdd(hp + 3, w * v.w);
    }
}

__global__ void k_relu(float* __restrict__ h, const float* __restrict__ b1, int n) {
    int i = blockIdx.x * blockDim.x + threadIdx.x;
    if (i < n) h[i] = fmaxf(h[i] + b1[i & (EDIM - 1)], 0.0f);
}

__global__ void k_outinit(float* __restrict__ out, const float* __restrict__ b2, int n) {
    int i = blockIdx.x * blockDim.x + threadIdx.x;
    if (i < n) out[i] = b2[i % CDIM];
}

// persistent blocks; w2 staged in LDS (f32, rows padded to 52 floats = 104 KB).
// one work item per (triple, c-quad): 13 quads cover C=50.
__global__ __launch_bounds__(1024, 1)
void k_spmm2(const int* __restrict__ fr, const int* __restrict__ to,
             const int* __restrict__ rel, const float* __restrict__ h,
             const float* __restrict__ w2, const float* __restrict__ inv,
             float* __restrict__ out, int T, int N, long long nitems) {
    extern __shared__ float lw2[];   // [RP*EDIM][LDSPAD]
    for (int j = threadIdx.x; j < RP * EDIM * CDIM; j += blockDim.x) {
        int row = j / CDIM;
        int c   = j - row * CDIM;
        lw2[row * LDSPAD + c] = w2[j];
    }
    __syncthreads();

    const int QC = (CDIM + 3) / 4;   // 13
    for (long long idx = (long long)blockIdx.x * blockDim.x + threadIdx.x;
         idx < nitems; idx += (long long)gridDim.x * blockDim.x) {
        int t  = (int)(idx / QC);
        int q  = (int)(idx - (long long)t * QC);
        int c0 = q * 4;
        int r = rel[t], f = fr[t], o = to[t];
        float w = inv[r * N + f];

        // h row -> registers (8x float4, same row broadcast across the 13 lanes of t)
        const float4* hp = reinterpret_cast<const float4*>(h + (size_t)o * EDIM);
        float hr[EDIM];
        #pragma unroll
        for (int i = 0; i < EDIM / 4; ++i) {
            float4 v = hp[i];
            hr[4 * i + 0] = v.x; hr[4 * i + 1] = v.y;
            hr[4 * i + 2] = v.z; hr[4 * i + 3] = v.w;
        }

        const float* base = lw2 + (r * EDIM) * LDSPAD + c0;
        float ax = 0.f, ay = 0.f, az = 0.f, aw = 0.f;
        #pragma unroll
        for (int e = 0; e < EDIM; ++e) {
            float4 wv = *reinterpret_cast<const float4*>(base + e * LDSPAD);
            ax += hr[e] * wv.x;
            ay += hr[e] * wv.y;
            az += hr[e] * wv.z;
            aw += hr[e] * wv.w;
        }

        float* op = out + (size_t)f * CDIM + c0;
        atomicAdd(op + 0, w * ax);
        atomicAdd(op + 1, w * ay);                       // c0+1 <= 49 always
        if (c0 + 2 < CDIM) atomicAdd(op + 2, w * az);
        if (c0 + 3 < CDIM) atomicAdd(op + 3, w * aw);
    }
}

extern "C" void kernel_launch(void* const* d_in, const int* in_sizes, int n_in,
                              void* d_out, int out_size, void* d_ws, size_t ws_size,
                              hipStream_t stream) {
    const int*   fr  = (const int*)d_in[0];
    const int*   to  = (const int*)d_in[1];
    const int*   rel = (const int*)d_in[2];
    const float* w1  = (const float*)d_in[3];
    const float* w2  = (const float*)d_in[4];
    const float* b1  = (const float*)d_in[5];
    const float* b2  = (const float*)d_in[6];
    float* out = (float*)d_out;

    const int T = in_sizes[0];
    const int N = in_sizes[3] / (RP * EDIM);

    // workspace layout: cnt (R*N int) | inv (R*N float) | h (N*E float)
    const size_t cnt_bytes = (size_t)RP * N * sizeof(int);
    int*   cnt = (int*)d_ws;
    float* inv = (float*)((char*)d_ws + cnt_bytes);
    float* h   = (float*)((char*)d_ws + 2 * cnt_bytes);

    hipMemsetAsync(cnt, 0, cnt_bytes, stream);
    hipMemsetAsync(h, 0, (size_t)N * EDIM * sizeof(float), stream);

    const int B = 256;
    k_count<<<(T + B - 1) / B, B, 0, stream>>>(fr, rel, cnt, T, N);
    k_inv<<<(RP * N + B - 1) / B, B, 0, stream>>>(cnt, inv, RP * N);

    long long n1 = (long long)T * (EDIM / 4);
    k_spmm1<<<(int)((n1 + B - 1) / B), B, 0, stream>>>(fr, to, rel, w1, inv, h, T, N);

    k_relu<<<(N * EDIM + B - 1) / B, B, 0, stream>>>(h, b1, N * EDIM);
    k_outinit<<<(out_size + B - 1) / B, B, 0, stream>>>(out, b2, out_size);

    const long long nitems = (long long)T * ((CDIM + 3) / 4);
    const size_t lds_bytes = (size_t)RP * EDIM * LDSPAD * sizeof(float);  // 106,496 B
    k_spmm2<<<256, 1024, lds_bytes, stream>>>(fr, to, rel, h, w2, inv, out, T, N, nitems);
}

// Round 3
// 223.778 us; speedup vs baseline: 2.0649x; 2.0649x over previous
//
#include <hip/hip_runtime.h>

// LGCN_REL_EMB: relational graph conv with identity relation embeddings.
//   cnt[r*N+v]  = #{t : rel[t]==r, fr[t]==v}
//   inv         = 1/cnt (0 where cnt==0)
//   h[v,:]      = relu(bias1 + sum_t inv[rel,fr] * w1[rel, to, :])   for fr[t]==v
//   out[v,c]    = bias2[c] + sum_t inv[rel,fr] * dot(h[to,:], w2[rel,:,c])  for fr[t]==v
//
// Fixed problem constants (from reference): R=16, E=32, C=50.
//
// Atomic-pattern rule (learned round 2): scatter to `out` must be ONE atomic
// instruction per thread with contiguous lanes covering one output row
// (thread = (t,c), 50 consecutive lanes share triple t). Splitting it into
// per-lane multi-atomics over interleaved rows caused per-line HBM RMW
// (594 MB fetch + 776 MB write).

#define RP 16
#define EDIM 32
#define CDIM 50

__global__ void k_count(const int* __restrict__ fr, const int* __restrict__ rel,
                        int* __restrict__ cnt, int T, int N) {
    int t = blockIdx.x * blockDim.x + threadIdx.x;
    if (t < T) atomicAdd(&cnt[rel[t] * N + fr[t]], 1);
}

__global__ void k_inv(const int* __restrict__ cnt, float* __restrict__ inv, int n) {
    int i = blockIdx.x * blockDim.x + threadIdx.x;
    if (i < n) {
        int c = cnt[i];
        inv[i] = (c > 0) ? 1.0f / (float)c : 0.0f;
    }
}

// one thread per (triple, e): h[fr*E + e] += inv * w1[(rel*N + to)*E + e]
// (round-1 form: 32 contiguous lanes share a triple -> coalesced atomic rows)
__global__ void k_spmm1(const int* __restrict__ fr, const int* __restrict__ to,
                        const int* __restrict__ rel, const float* __restrict__ w1,
                        const float* __restrict__ inv, float* __restrict__ h,
                        int T, int N) {
    int idx = blockIdx.x * blockDim.x + threadIdx.x;
    int t = idx >> 5;
    int e = idx & (EDIM - 1);
    if (t < T) {
        int r = rel[t], f = fr[t], o = to[t];
        float w = inv[r * N + f];
        float v = w * w1[((size_t)r * N + o) * EDIM + e];
        atomicAdd(&h[(size_t)f * EDIM + e], v);
    }
}

__global__ void k_relu(float* __restrict__ h, const float* __restrict__ b1, int n) {
    int i = blockIdx.x * blockDim.x + threadIdx.x;
    if (i < n) h[i] = fmaxf(h[i] + b1[i & (EDIM - 1)], 0.0f);
}

__global__ void k_outinit(float* __restrict__ out, const float* __restrict__ b2, int n) {
    int i = blockIdx.x * blockDim.x + threadIdx.x;
    if (i < n) out[i] = b2[i % CDIM];
}

// thread = (t, c) exactly like round 1; flat grid; single trailing atomic.
// Changes vs round 1: h row via 8 broadcast float4 loads; w2 staged in LDS
// (unpadded [r][e][c], c-contiguous: lane c -> consecutive banks, conflict-free).
__global__ __launch_bounds__(1024, 1)
void k_spmm2(const int* __restrict__ fr, const int* __restrict__ to,
             const int* __restrict__ rel, const float* __restrict__ h,
             const float* __restrict__ w2, const float* __restrict__ inv,
             float* __restrict__ out, int T, int N) {
    extern __shared__ float lw2[];   // RP*EDIM*CDIM = 25600 floats = 102.4 KB
    for (int j = threadIdx.x; j < RP * EDIM * CDIM; j += 1024) lw2[j] = w2[j];
    __syncthreads();

    int idx = blockIdx.x * 1024 + threadIdx.x;
    int t = idx / CDIM;
    int c = idx - t * CDIM;
    if (t >= T) return;

    int r = rel[t], f = fr[t], o = to[t];
    float w = inv[r * N + f];

    // h row -> registers (broadcast across the 50 lanes sharing t)
    const float4* __restrict__ hp = reinterpret_cast<const float4*>(h + (size_t)o * EDIM);
    float hr[EDIM];
    #pragma unroll
    for (int i = 0; i < EDIM / 4; ++i) {
        float4 v = hp[i];
        hr[4 * i + 0] = v.x; hr[4 * i + 1] = v.y;
        hr[4 * i + 2] = v.z; hr[4 * i + 3] = v.w;
    }

    const float* base = lw2 + r * (EDIM * CDIM) + c;
    float acc = 0.0f;
    #pragma unroll
    for (int e = 0; e < EDIM; ++e) {
        acc += hr[e] * base[e * CDIM];
    }

    atomicAdd(&out[(size_t)f * CDIM + c], w * acc);
}

extern "C" void kernel_launch(void* const* d_in, const int* in_sizes, int n_in,
                              void* d_out, int out_size, void* d_ws, size_t ws_size,
                              hipStream_t stream) {
    const int*   fr  = (const int*)d_in[0];
    const int*   to  = (const int*)d_in[1];
    const int*   rel = (const int*)d_in[2];
    const float* w1  = (const float*)d_in[3];
    const float* w2  = (const float*)d_in[4];
    const float* b1  = (const float*)d_in[5];
    const float* b2  = (const float*)d_in[6];
    float* out = (float*)d_out;

    const int T = in_sizes[0];
    const int N = in_sizes[3] / (RP * EDIM);

    // workspace layout: cnt (R*N int) | inv (R*N float) | h (N*E float)
    const size_t cnt_bytes = (size_t)RP * N * sizeof(int);
    int*   cnt = (int*)d_ws;
    float* inv = (float*)((char*)d_ws + cnt_bytes);
    float* h   = (float*)((char*)d_ws + 2 * cnt_bytes);

    hipMemsetAsync(cnt, 0, cnt_bytes, stream);
    hipMemsetAsync(h, 0, (size_t)N * EDIM * sizeof(float), stream);

    const int B = 256;
    k_count<<<(T + B - 1) / B, B, 0, stream>>>(fr, rel, cnt, T, N);
    k_inv<<<(RP * N + B - 1) / B, B, 0, stream>>>(cnt, inv, RP * N);

    long long n1 = (long long)T * EDIM;
    k_spmm1<<<(int)((n1 + B - 1) / B), B, 0, stream>>>(fr, to, rel, w1, inv, h, T, N);

    k_relu<<<(N * EDIM + B - 1) / B, B, 0, stream>>>(h, b1, N * EDIM);
    k_outinit<<<(out_size + B - 1) / B, B, 0, stream>>>(out, b2, out_size);

    long long n2 = (long long)T * CDIM;
    const size_t lds_bytes = (size_t)RP * EDIM * CDIM * sizeof(float);  // 102400 B
    k_spmm2<<<(int)((n2 + 1023) / 1024), 1024, lds_bytes, stream>>>(
        fr, to, rel, h, w2, inv, out, T, N);
}

// Round 4
// 181.437 us; speedup vs baseline: 2.5468x; 1.2334x over previous
//
#include <hip/hip_runtime.h>

// LGCN_REL_EMB: relational graph conv with identity relation embeddings.
//   cnt[r*N+v]  = #{t : rel[t]==r, fr[t]==v}
//   inv         = 1/cnt (0 where cnt==0)
//   h[v,:]      = relu(bias1 + sum_t inv[rel,fr] * w1[rel, to, :])   for fr[t]==v
//   out[v,c]    = bias2[c] + sum_t inv[rel,fr] * dot(h[to,:], w2[rel,:,c])  for fr[t]==v
//
// Structure (round 4): counting-sort triples by relation (padded to CH-multiples
// with zero-weight dummies) so each spmm2 block is single-relation and each lane
// holds one w2 column in registers. Atomic rule (round 2): one atomic instr per
// thread, contiguous lanes covering one output row.

#define RP 16
#define EDIM 32
#define CDIM 50
#define CH 64            // triples per chunk (uniform relation per chunk)

// ---- count: cnt[r*N+f]++ and per-relation totals (block LDS histogram)
__global__ void k_count(const int* __restrict__ fr, const int* __restrict__ rel,
                        int* __restrict__ cnt, int* __restrict__ reltot,
                        int T, int N) {
    __shared__ int lhist[RP];
    if (threadIdx.x < RP) lhist[threadIdx.x] = 0;
    __syncthreads();
    int t = blockIdx.x * blockDim.x + threadIdx.x;
    if (t < T) {
        int r = rel[t];
        atomicAdd(&cnt[r * N + fr[t]], 1);
        atomicAdd(&lhist[r], 1);
    }
    __syncthreads();
    if (threadIdx.x < RP && lhist[threadIdx.x] > 0)
        atomicAdd(&reltot[threadIdx.x], lhist[threadIdx.x]);
}

// ---- tiny scan: padded segment starts -> cursor (scatter) ; run by 1 thread
__global__ void k_scan(const int* __restrict__ reltot, int* __restrict__ cursor) {
    if (blockIdx.x == 0 && threadIdx.x == 0) {
        int acc = 0;
        for (int r = 0; r < RP; ++r) {
            cursor[r] = acc;
            acc += ((reltot[r] + CH - 1) / CH) * CH;
        }
    }
}

// ---- inv in place over cnt (int -> float, same buffer)
__global__ void k_inv(int* __restrict__ cnt, int n) {
    int i = blockIdx.x * blockDim.x + threadIdx.x;
    if (i < n) {
        int c = cnt[i];
        float v = (c > 0) ? 1.0f / (float)c : 0.0f;
        ((float*)cnt)[i] = v;
    }
}

// ---- scatter into relation-sorted arrays (block hist + rank, 16 global atomics/blk)
__global__ void k_scatter(const int* __restrict__ fr, const int* __restrict__ to,
                          const int* __restrict__ rel, const float* __restrict__ inv,
                          int* __restrict__ cursor,
                          int* __restrict__ sfr, int* __restrict__ sto,
                          int* __restrict__ srel, float* __restrict__ sw,
                          int T, int N) {
    __shared__ int lhist[RP];
    __shared__ int lbase[RP];
    if (threadIdx.x < RP) lhist[threadIdx.x] = 0;
    __syncthreads();
    int t = blockIdx.x * blockDim.x + threadIdx.x;
    int r = 0, rank = 0;
    bool live = (t < T);
    if (live) {
        r = rel[t];
        rank = atomicAdd(&lhist[r], 1);
    }
    __syncthreads();
    if (threadIdx.x < RP) {
        int c = lhist[threadIdx.x];
        lbase[threadIdx.x] = (c > 0) ? atomicAdd(&cursor[threadIdx.x], c) : 0;
    }
    __syncthreads();
    if (live) {
        int pos = lbase[r] + rank;
        int f = fr[t];
        sfr[pos] = f;
        sto[pos] = to[t];
        srel[pos] = r;
        sw[pos] = inv[r * N + f];
    }
}

// ---- spmm1 over sorted triples: h[fr,:] += w * w1[rel, to, :]
__global__ void k_spmm1(const int* __restrict__ sfr, const int* __restrict__ sto,
                        const int* __restrict__ srel, const float* __restrict__ sw,
                        const float* __restrict__ w1, float* __restrict__ h,
                        int M, int N) {
    int idx = blockIdx.x * blockDim.x + threadIdx.x;
    int t = idx >> 5;
    int e = idx & (EDIM - 1);
    if (t < M) {
        float w = sw[t];
        if (w != 0.0f) {
            int r = srel[t], f = sfr[t], o = sto[t];
            float v = w * w1[((size_t)r * N + o) * EDIM + e];
            atomicAdd(&h[(size_t)f * EDIM + e], v);
        }
    }
}

__global__ void k_relu(float* __restrict__ h, const float* __restrict__ b1, int n) {
    int i = blockIdx.x * blockDim.x + threadIdx.x;
    if (i < n) h[i] = fmaxf(h[i] + b1[i & (EDIM - 1)], 0.0f);
}

__global__ void k_outinit(float* __restrict__ out, const float* __restrict__ b2, int n) {
    int i = blockIdx.x * blockDim.x + threadIdx.x;
    if (i < n) out[i] = b2[i % CDIM];
}

// ---- spmm2: block = one CH-triple chunk of ONE relation. Lane holds w2 column
// (32 regs); per triple: 8 broadcast float4 h-loads + 32 FMA + 1 row atomic.
__global__ __launch_bounds__(256)
void k_spmm2(const int* __restrict__ sfr, const int* __restrict__ sto,
             const int* __restrict__ srel, const float* __restrict__ sw,
             const float* __restrict__ h, const float* __restrict__ w2,
             float* __restrict__ out) {
    const int base = blockIdx.x * CH;
    const int lane = threadIdx.x & 63;
    const int wv   = threadIdx.x >> 6;          // 0..3
    const int r    = srel[base];                // uniform over the chunk

    // this lane's w2 column (clamped for lanes 50..63; they never store)
    float w2c[EDIM];
    {
        const float* p = w2 + r * (EDIM * CDIM) + (lane < CDIM ? lane : CDIM - 1);
        #pragma unroll
        for (int e = 0; e < EDIM; ++e) w2c[e] = p[e * CDIM];
    }

    for (int i = base + wv; i < base + CH; i += 4) {
        float w = sw[i];                         // 0.0 for pad entries
        int o = sto[i];
        int f = sfr[i];
        const float4* __restrict__ hp = reinterpret_cast<const float4*>(h + (size_t)o * EDIM);
        float4 hv[EDIM / 4];
        #pragma unroll
        for (int q = 0; q < EDIM / 4; ++q) hv[q] = hp[q];
        float acc = 0.0f;
        #pragma unroll
        for (int q = 0; q < EDIM / 4; ++q) {
            acc = fmaf(hv[q].x, w2c[4 * q + 0], acc);
            acc = fmaf(hv[q].y, w2c[4 * q + 1], acc);
            acc = fmaf(hv[q].z, w2c[4 * q + 2], acc);
            acc = fmaf(hv[q].w, w2c[4 * q + 3], acc);
        }
        if (w != 0.0f && lane < CDIM)
            atomicAdd(&out[(size_t)f * CDIM + lane], w * acc);
    }
}

extern "C" void kernel_launch(void* const* d_in, const int* in_sizes, int n_in,
                              void* d_out, int out_size, void* d_ws, size_t ws_size,
                              hipStream_t stream) {
    const int*   fr  = (const int*)d_in[0];
    const int*   to  = (const int*)d_in[1];
    const int*   rel = (const int*)d_in[2];
    const float* w1  = (const float*)d_in[3];
    const float* w2  = (const float*)d_in[4];
    const float* b1  = (const float*)d_in[5];
    const float* b2  = (const float*)d_in[6];
    float* out = (float*)d_out;

    const int T = in_sizes[0];
    const int N = in_sizes[3] / (RP * EDIM);

    const int nchunks = (T + CH - 1) / CH + RP;   // upper bound incl. padding
    const int SMAX    = nchunks * CH;

    // ws layout: cnt/inv (R*N, in-place) | meta (reltot[16]+cursor[16]) | h (N*E)
    //            | sfr | sto | srel | sw  (SMAX each, contiguous)
    char* p = (char*)d_ws;
    int*   cnt    = (int*)p;                         p += (size_t)RP * N * sizeof(int);
    int*   reltot = (int*)p;                         p += 16 * sizeof(int);
    int*   cursor = (int*)p;                         p += 16 * sizeof(int);
    p = (char*)(((size_t)p + 255) & ~(size_t)255);
    float* h      = (float*)p;                       p += (size_t)N * EDIM * sizeof(float);
    int*   sfr    = (int*)p;                         p += (size_t)SMAX * sizeof(int);
    int*   sto    = (int*)p;                         p += (size_t)SMAX * sizeof(int);
    int*   srel   = (int*)p;                         p += (size_t)SMAX * sizeof(int);
    float* sw     = (float*)p;                       p += (size_t)SMAX * sizeof(float);
    float* inv    = (float*)cnt;                     // in-place after k_inv

    hipMemsetAsync(cnt, 0, (size_t)RP * N * sizeof(int) + 32 * sizeof(int), stream);
    hipMemsetAsync(h, 0, (size_t)N * EDIM * sizeof(float), stream);
    hipMemsetAsync(sfr, 0, (size_t)SMAX * 4 * sizeof(int), stream);

    const int B = 256;
    k_count<<<(T + B - 1) / B, B, 0, stream>>>(fr, rel, cnt, reltot, T, N);
    k_scan<<<1, 64, 0, stream>>>(reltot, cursor);
    k_inv<<<(RP * N + B - 1) / B, B, 0, stream>>>(cnt, RP * N);
    k_scatter<<<(T + B - 1) / B, B, 0, stream>>>(fr, to, rel, inv, cursor,
                                                 sfr, sto, srel, sw, T, N);

    long long n1 = (long long)SMAX * EDIM;
    k_spmm1<<<(int)((n1 + B - 1) / B), B, 0, stream>>>(sfr, sto, srel, sw, w1, h, SMAX, N);

    k_relu<<<(N * EDIM + B - 1) / B, B, 0, stream>>>(h, b1, N * EDIM);
    k_outinit<<<(out_size + B - 1) / B, B, 0, stream>>>(out, b2, out_size);

    k_spmm2<<<nchunks, 256, 0, stream>>>(sfr, sto, srel, sw, h, w2, out);
}